// Round 1
// baseline (241.867 us; speedup 1.0000x reference)
//
#include <hip/hip_runtime.h>
#include <math.h>

namespace {

constexpr int kB  = 2;
constexpr int kN  = 192;
constexpr int kC  = 32;
constexpr int kH  = 64;
constexpr int kNB = 20;
constexpr int kLayers = 2;

// G[z,b,h,i] = sum_j W2[h, i*C + j] * feat[z,b,j]
__global__ __launch_bounds__(256) void g_kernel(
    const float* __restrict__ feat,   // [B*N, C]
    const float* __restrict__ W2,     // [H, C*C]
    float* __restrict__ G)            // [B*N, H*C]
{
    __shared__ float fsh[kC];
    const int zb  = blockIdx.x;
    const int tid = threadIdx.x;
    if (tid < kC) fsh[tid] = feat[zb * kC + tid];
    __syncthreads();
#pragma unroll
    for (int r = 0; r < (kH * kC) / 256; ++r) {
        const int idx = tid + 256 * r;                 // idx = h*32 + i
        const float* w = W2 + (idx >> 5) * (kC * kC) + (idx & 31) * kC;
        float s = 0.f;
#pragma unroll
        for (int j = 0; j < kC; ++j) s = fmaf(w[j], fsh[j], s);
        G[zb * (kH * kC) + idx] = s;
    }
}

// S[z,j] = sum_b feat[z,b,j]
__global__ void s_kernel(const float* __restrict__ feat, float* __restrict__ S)
{
    const int z = blockIdx.x;
    const int j = threadIdx.x;
    if (j < kC) {
        float s = 0.f;
        for (int b = 0; b < kN; ++b) s += feat[(z * kN + b) * kC + j];
        S[z * kC + j] = s;
    }
}

// One block per (z,a). 4 waves; wave w handles b = 4*it + w.
__global__ __launch_bounds__(256) void conv_kernel(
    const float* __restrict__ xyz,    // [B,N,3]
    const float* __restrict__ mask,   // [B,N]
    const float* __restrict__ W0,     // [NB,H]
    const float* __restrict__ b0,     // [H]
    const float* __restrict__ W1,     // [H,H]
    const float* __restrict__ b1,     // [H]
    const float* __restrict__ b2,     // [C*C]
    const float* __restrict__ G,      // [B*N, H*C]
    const float* __restrict__ S,      // [B,C]
    float* __restrict__ out)          // [B,N,C]
{
    __shared__ float rb_sh[kN][kNB];  // 15360 B (rows 80 B -> 16B aligned)
    __shared__ float h1_sh[4][kH];
    __shared__ float red_sh[4][kC];

    const int tid  = threadIdx.x;
    const int wave = tid >> 6;
    const int lane = tid & 63;
    const int z = blockIdx.x / kN;
    const int a = blockIdx.x - z * kN;

    const float ax = xyz[(z * kN + a) * 3 + 0];
    const float ay = xyz[(z * kN + a) * 3 + 1];
    const float az = xyz[(z * kN + a) * 3 + 2];

    constexpr float kStep    = 10.0f / 19.0f;
    constexpr float kInvStep = 19.0f / 10.0f;
    if (tid < kN) {
        const int b = tid;
        const float dx = xyz[(z * kN + b) * 3 + 0] - ax;
        const float dy = xyz[(z * kN + b) * 3 + 1] - ay;
        const float dz = xyz[(z * kN + b) * 3 + 2] - az;
        const float d  = sqrtf(fmaf(dx, dx, fmaf(dy, dy, fmaf(dz, dz, 1e-12f))));
#pragma unroll
        for (int k = 0; k < kNB; ++k) {
            float y = (d - kStep * (float)k) * kInvStep;
            y = fminf(1.f, fmaxf(-1.f, y));
            rb_sh[b][k] = __cosf(1.57079632679f * y);
        }
    }

    // Per-lane weight columns (h = lane)
    float w0c[kNB];
#pragma unroll
    for (int k = 0; k < kNB; ++k) w0c[k] = W0[k * kH + lane];
    float w1c[kH];
#pragma unroll
    for (int k = 0; k < kH; ++k) w1c[k] = W1[k * kH + lane];
    const float b0v = b0[lane];
    const float b1v = b1[lane];

    float acc[kC];
#pragma unroll
    for (int i = 0; i < kC; ++i) acc[i] = 0.f;

    __syncthreads();   // rb_sh ready (cross-wave)

    for (int it = 0; it < kN / 4; ++it) {
        const int b = (it << 2) | wave;
        // h1[lane] for edge (a,b)
        float s = b0v;
#pragma unroll
        for (int k = 0; k < kNB; ++k) s = fmaf(rb_sh[b][k], w0c[k], s);
        h1_sh[wave][lane] = fmaxf(s, 0.f);
        __builtin_amdgcn_wave_barrier();   // wave-internal LDS ordering only
        // h2[lane]
        float t = b1v;
#pragma unroll
        for (int k = 0; k < kH; ++k) t = fmaf(h1_sh[wave][k], w1c[k], t);
        const float h2 = fmaxf(t, 0.f);
        // acc[i] += h2 * G[z,b,lane,i]
        const float* g = G + ((size_t)(z * kN + b) * kH + lane) * kC;
#pragma unroll
        for (int i = 0; i < kC; ++i) acc[i] = fmaf(h2, g[i], acc[i]);
        __builtin_amdgcn_wave_barrier();
    }

    // Reduce acc over 64 lanes (butterfly), then over 4 waves via LDS
#pragma unroll
    for (int i = 0; i < kC; ++i) {
        float v = acc[i];
#pragma unroll
        for (int off = 32; off > 0; off >>= 1) v += __shfl_xor(v, off, 64);
        acc[i] = v;
    }
    if (lane == 0) {
#pragma unroll
        for (int i = 0; i < kC; ++i) red_sh[wave][i] = acc[i];
    }
    __syncthreads();
    if (tid < kC) {
        const int i = tid;
        float v = red_sh[0][i] + red_sh[1][i] + red_sh[2][i] + red_sh[3][i];
        float bt = 0.f;
#pragma unroll
        for (int j = 0; j < kC; ++j) bt = fmaf(b2[i * kC + j], S[z * kC + j], bt);
        constexpr float kInvSqrtN = 0.07216878364870323f;  // 1/sqrt(192)
        v = (v + bt) * kInvSqrtN * mask[z * kN + a];
        out[(z * kN + a) * kC + i] = v;
    }
}

} // namespace

extern "C" void kernel_launch(void* const* d_in, const int* in_sizes, int n_in,
                              void* d_out, int out_size, void* d_ws, size_t ws_size,
                              hipStream_t stream) {
    const float* features = (const float*)d_in[0];
    const float* xyz      = (const float*)d_in[1];
    const float* mask     = (const float*)d_in[2];
    const float* W0       = (const float*)d_in[3];
    const float* b0       = (const float*)d_in[4];
    const float* W1       = (const float*)d_in[5];
    const float* b1       = (const float*)d_in[6];
    const float* W2       = (const float*)d_in[7];
    const float* b2       = (const float*)d_in[8];
    float* out = (float*)d_out;

    char* ws = (char*)d_ws;
    float* G    = (float*)ws;                              // B*N*H*C = 786432 f
    float* S    = (float*)(ws + 786432 * 4);               // 64 f (pad to 256 B)
    float* ftmp = (float*)(ws + 786432 * 4 + 256);         // B*N*C = 12288 f

    const float* cur = features;
    for (int l = 0; l < kLayers; ++l) {
        float* dst = (l == kLayers - 1) ? out : ftmp;
        g_kernel<<<kB * kN, 256, 0, stream>>>(cur, W2 + (size_t)l * kH * kC * kC, G);
        s_kernel<<<kB, 64, 0, stream>>>(cur, S);
        conv_kernel<<<kB * kN, 256, 0, stream>>>(
            xyz, mask,
            W0 + (size_t)l * kNB * kH, b0 + (size_t)l * kH,
            W1 + (size_t)l * kH * kH,  b1 + (size_t)l * kH,
            b2 + (size_t)l * kC * kC,
            G, S, dst);
        cur = dst;
    }
}